// Round 5
// baseline (62.265 us; speedup 1.0000x reference)
//
#include <hip/hip_runtime.h>
#include <hip/hip_bf16.h>
#include <hip/hip_fp16.h>

#define BB 8
#define NN 1024
#define FIN 128
#define FOUT 64
#define HH 4
#define EPSV 1e-7f
#define SLOPE 0.2f
#define LOG2E 1.44269504088896340736f

typedef _Float16 v8h __attribute__((ext_vector_type(8)));
typedef _Float16 v4h __attribute__((ext_vector_type(4)));
typedef float v4f __attribute__((ext_vector_type(4)));

// ---------------- K0: Wtt[ct][kgg][16][8]: (ct*16+ln, kgg*8+e) of Wt --------
__global__ __launch_bounds__(256) void k0_wt(const float* __restrict__ W,
                                             _Float16* __restrict__ Wtt) {
  for (int it = 0; it < 16; ++it) {
    int idx = blockIdx.x * 4096 + it * 256 + threadIdx.x;
    int e = idx & 7, ln = (idx >> 3) & 15, kgg = (idx >> 7) & 15,
        ct = idx >> 11;
    int c = ct * 16 + ln, k = kgg * 8 + e;
    Wtt[idx] = (_Float16)W[(size_t)(c >> 6) * 8192 + k * 64 + (c & 63)];
  }
}

// ---------------- K1: Wh = x @ W via MFMA f16 + fused s_i/s_j ---------------
__global__ __launch_bounds__(256) void k1_whm(const float* __restrict__ x,
                                              const _Float16* __restrict__ Wtt,
                                              const float* __restrict__ aw,
                                              const float* __restrict__ ab,
                                              _Float16* __restrict__ WhH,
                                              float* __restrict__ si2,
                                              float* __restrict__ tj2) {
  __shared__ _Float16 xs[16][136];
  int tid = threadIdx.x;
#pragma unroll
  for (int t2 = 0; t2 < 2; ++t2) {
    int idx = t2 * 256 + tid;
    int row = idx >> 5, c4 = (idx & 31) * 4;
    float4 v = *(const float4*)(x + ((size_t)blockIdx.x * 16 + row) * FIN + c4);
    v4h hv;
    hv[0] = (_Float16)v.x; hv[1] = (_Float16)v.y;
    hv[2] = (_Float16)v.z; hv[3] = (_Float16)v.w;
    *(v4h*)(&xs[row][c4]) = hv;
  }
  __syncthreads();
  int w = tid >> 6, l = tid & 63;
  int kg = l >> 4, ln = l & 15;
  v4f acc[4] = {{}, {}, {}, {}};
#pragma unroll
  for (int ks = 0; ks < 4; ++ks) {
    v8h af = *(const v8h*)(&xs[ln][ks * 32 + kg * 8]);
    int kgg = ks * 4 + kg;
#pragma unroll
    for (int t = 0; t < 4; ++t) {
      int ct = w * 4 + t;
      v8h bf = *(const v8h*)(Wtt + (((size_t)ct * 16 + kgg) * 16 + ln) * 8);
      acc[t] = __builtin_amdgcn_mfma_f32_16x16x32_f16(af, bf, acc[t], 0, 0, 0);
    }
  }
  float a1v[4], a2v[4];
#pragma unroll
  for (int t = 0; t < 4; ++t) {
    a1v[t] = aw[w * 128 + t * 16 + ln];
    a2v[t] = aw[w * 128 + 64 + t * 16 + ln];
  }
  float abv = ab[w];
#pragma unroll
  for (int r = 0; r < 4; ++r) {
    float v1 = acc[0][r] * a1v[0] + acc[1][r] * a1v[1] +
               acc[2][r] * a1v[2] + acc[3][r] * a1v[3];
    float v2 = acc[0][r] * a2v[0] + acc[1][r] * a2v[1] +
               acc[2][r] * a2v[2] + acc[3][r] * a2v[3];
#pragma unroll
    for (int off = 1; off < 16; off <<= 1) {
      v1 += __shfl_xor(v1, off);
      v2 += __shfl_xor(v2, off);
    }
    if (ln == 0) {
      int gr = blockIdx.x * 16 + kg * 4 + r;
      int b_ = gr >> 10, n_ = gr & 1023;
      size_t row = ((size_t)b_ * HH + w) * NN + n_;
      si2[row] = v1 * LOG2E;
      tj2[row] = (v2 + abv) * LOG2E;
    }
  }
#pragma unroll
  for (int t = 0; t < 4; ++t) {
#pragma unroll
    for (int r = 0; r < 4; ++r) {
      int gr = blockIdx.x * 16 + kg * 4 + r;
      int b_ = gr >> 10, n_ = gr & 1023;
      WhH[(((size_t)b_ * HH + w) * NN + n_) * 64 + (t * 16 + ln)] =
          (_Float16)acc[t][r];
    }
  }
}

// ------- KB: column sums of exps over i (16 splits of 64) + A bit-pack ------
// grid (4 jt, 16 is, B), block 256. Also writes Abits[b*N+i][16] (u64 words).
__global__ __launch_bounds__(256) void kb_colsum_bits(
    const float* __restrict__ A, const float* __restrict__ si2,
    const float* __restrict__ tj2, float* __restrict__ part,
    unsigned long long* __restrict__ Abits) {
  __shared__ float sil[4][64];
  int b = blockIdx.z, is = blockIdx.y, jt = blockIdx.x;
  int tid = threadIdx.x;
  int w = tid >> 6;
  int j = jt * 256 + tid;
  int i0 = is * 64;
  if (tid < 256) {
    int h = tid >> 6, ii = tid & 63;
    sil[h][ii] = si2[((size_t)(b * HH + h)) * NN + i0 + ii];
  }
  __syncthreads();
  float tjv[4], acc[4] = {0.f, 0.f, 0.f, 0.f};
#pragma unroll
  for (int h = 0; h < 4; ++h) tjv[h] = tj2[((size_t)(b * HH + h)) * NN + j];
  const float* Ap = A + ((size_t)b * NN + i0) * NN + j;
#pragma unroll 4
  for (int ii = 0; ii < 64; ++ii) {
    float a = Ap[(size_t)ii * NN];
    unsigned long long m = __ballot(a != 0.0f);
    if ((tid & 63) == 0)
      Abits[((size_t)b * NN + i0 + ii) * 16 + jt * 4 + w] = m;
#pragma unroll
    for (int h = 0; h < 4; ++h) {
      float f = sil[h][ii] + tjv[h];
      float g = fmaxf(f, SLOPE * f);
      acc[h] += a * __builtin_amdgcn_exp2f(g);
    }
  }
#pragma unroll
  for (int h = 0; h < 4; ++h)
    part[((size_t)(is * 32) + b * HH + h) * NN + j] = acc[h];
}

// ---------------- K3: r[j]=1/(colsum+eps); VTt[bh][jb][o][jj] = (f16) r*Wh --
__global__ __launch_bounds__(256) void k3_scale_tr(
    const _Float16* __restrict__ WhH, const float* __restrict__ part,
    _Float16* __restrict__ VTt) {
  __shared__ float rbuf[64];
  __shared__ _Float16 tile[64 * 66];
  int bid = blockIdx.x;
  int b = bid & 7, rest = bid >> 3;
  int h = rest & 3, jt = rest >> 2;
  int bh = b * HH + h, j0 = jt * 64;
  int tid = threadIdx.x;
  if (tid < 64) {
    float s = 0.f;
#pragma unroll
    for (int is = 0; is < 16; ++is)
      s += part[((size_t)(is * 32) + bh) * NN + j0 + tid];
    rbuf[tid] = 1.0f / (s + EPSV);
  }
  __syncthreads();
#pragma unroll
  for (int it = 0; it < 16; ++it) {
    int lin = it * 256 + tid;
    int jj = lin >> 6, o = lin & 63;
    float v = (float)WhH[((size_t)bh * NN + j0 + jj) * 64 + o] * rbuf[jj];
    tile[o * 66 + jj] = (_Float16)v;
  }
  __syncthreads();
#pragma unroll
  for (int it = 0; it < 16; ++it) {
    int lin = it * 256 + tid;
    int o = lin >> 6, jj64 = lin & 63;
    int j = j0 + jj64;
    int jb = j >> 5, jj = j & 31;
    VTt[(((size_t)bh * 32 + jb) * 64 + o) * 32 + jj] = tile[o * 66 + jj64];
  }
}

// ---------------- K4: out[i,:] = sum_j P[i,j] * V'[j,:] via MFMA ------------
// grid 256 1D (b = bid&7 -> XCD-local VT), block 512 = 8 waves.
// wave w: head = w&3, j-half = w>>2 (512 js). 32 i-rows per block from Abits.
// Cross-wave (j-half) O reduction in LDS.
__global__ __launch_bounds__(512) void k4_pv(
    const unsigned long long* __restrict__ Abits,
    const float* __restrict__ si2, const float* __restrict__ tj2,
    const _Float16* __restrict__ VTt, float* __restrict__ out) {
  __shared__ unsigned long long Ab[32][17];
  __shared__ float tjl[4][1024];
  __shared__ float sil[4][32];
  __shared__ float red[4][64][33];
  int bid = blockIdx.x;
  int b = bid & 7, it = bid >> 3;
  int i0 = it * 32;
  int tid = threadIdx.x;
#pragma unroll
  for (int t2 = 0; t2 < 8; ++t2) {
    int idx = t2 * 512 + tid;
    int h = idx >> 10, j = idx & 1023;
    tjl[h][j] = tj2[((size_t)(b * HH + h)) * NN + j];
  }
  if (tid < 128) {
    int h = tid >> 5, ii = tid & 31;
    sil[h][ii] = si2[((size_t)(b * HH + h)) * NN + i0 + ii];
  }
  {
    int row = tid >> 4, word = tid & 15;
    Ab[row][word] = Abits[((size_t)b * NN + i0 + row) * 16 + word];
  }
  __syncthreads();

  int w = tid >> 6, l = tid & 63;
  int h = w & 3, jh = w >> 2;
  int kg = l >> 4, ln = l & 15;
  float si0 = sil[h][ln];
  float si1 = sil[h][16 + ln];
  int bh = b * HH + h;
  v4f acc0[4] = {{}, {}, {}, {}};
  v4f acc1[4] = {{}, {}, {}, {}};
  const _Float16* VTb = VTt + (size_t)bh * 32 * 64 * 32;
  const float* tj = tjl[h];
  int jbase = jh * 512;

#define PEXP(si, tv) \
  __builtin_amdgcn_exp2f(fmaxf((si) + (tv), SLOPE * ((si) + (tv))))

#pragma unroll 2
  for (int jq = 0; jq < 16; ++jq) {
    int j = jbase + jq * 32 + kg * 8;
    int widx = j >> 6, sh = j & 63;
    unsigned int bits0 = (unsigned int)(Ab[ln][widx] >> sh) & 0xffu;
    unsigned int bits1 = (unsigned int)(Ab[16 + ln][widx] >> sh) & 0xffu;
    float4 t0 = *(const float4*)(tj + j);
    float4 t1 = *(const float4*)(tj + j + 4);
    v8h af0, af1;
    af0[0] = (bits0 & 1u) ? (_Float16)PEXP(si0, t0.x) : (_Float16)0;
    af0[1] = (bits0 & 2u) ? (_Float16)PEXP(si0, t0.y) : (_Float16)0;
    af0[2] = (bits0 & 4u) ? (_Float16)PEXP(si0, t0.z) : (_Float16)0;
    af0[3] = (bits0 & 8u) ? (_Float16)PEXP(si0, t0.w) : (_Float16)0;
    af0[4] = (bits0 & 16u) ? (_Float16)PEXP(si0, t1.x) : (_Float16)0;
    af0[5] = (bits0 & 32u) ? (_Float16)PEXP(si0, t1.y) : (_Float16)0;
    af0[6] = (bits0 & 64u) ? (_Float16)PEXP(si0, t1.z) : (_Float16)0;
    af0[7] = (bits0 & 128u) ? (_Float16)PEXP(si0, t1.w) : (_Float16)0;
    af1[0] = (bits1 & 1u) ? (_Float16)PEXP(si1, t0.x) : (_Float16)0;
    af1[1] = (bits1 & 2u) ? (_Float16)PEXP(si1, t0.y) : (_Float16)0;
    af1[2] = (bits1 & 4u) ? (_Float16)PEXP(si1, t0.z) : (_Float16)0;
    af1[3] = (bits1 & 8u) ? (_Float16)PEXP(si1, t0.w) : (_Float16)0;
    af1[4] = (bits1 & 16u) ? (_Float16)PEXP(si1, t1.x) : (_Float16)0;
    af1[5] = (bits1 & 32u) ? (_Float16)PEXP(si1, t1.y) : (_Float16)0;
    af1[6] = (bits1 & 64u) ? (_Float16)PEXP(si1, t1.z) : (_Float16)0;
    af1[7] = (bits1 & 128u) ? (_Float16)PEXP(si1, t1.w) : (_Float16)0;
    const _Float16* vb = VTb + (size_t)(j >> 5) * 2048 + kg * 8;
    v8h b0 = *(const v8h*)(vb + (0 * 16 + ln) * 32);
    v8h b1 = *(const v8h*)(vb + (1 * 16 + ln) * 32);
    v8h b2 = *(const v8h*)(vb + (2 * 16 + ln) * 32);
    v8h b3 = *(const v8h*)(vb + (3 * 16 + ln) * 32);
    acc0[0] = __builtin_amdgcn_mfma_f32_16x16x32_f16(af0, b0, acc0[0], 0, 0, 0);
    acc1[0] = __builtin_amdgcn_mfma_f32_16x16x32_f16(af1, b0, acc1[0], 0, 0, 0);
    acc0[1] = __builtin_amdgcn_mfma_f32_16x16x32_f16(af0, b1, acc0[1], 0, 0, 0);
    acc1[1] = __builtin_amdgcn_mfma_f32_16x16x32_f16(af1, b1, acc1[1], 0, 0, 0);
    acc0[2] = __builtin_amdgcn_mfma_f32_16x16x32_f16(af0, b2, acc0[2], 0, 0, 0);
    acc1[2] = __builtin_amdgcn_mfma_f32_16x16x32_f16(af1, b2, acc1[2], 0, 0, 0);
    acc0[3] = __builtin_amdgcn_mfma_f32_16x16x32_f16(af0, b3, acc0[3], 0, 0, 0);
    acc1[3] = __builtin_amdgcn_mfma_f32_16x16x32_f16(af1, b3, acc1[3], 0, 0, 0);
  }
#undef PEXP

  // j-half 1 waves dump to LDS; j-half 0 waves combine + store
  if (jh) {
#pragma unroll
    for (int t = 0; t < 4; ++t)
#pragma unroll
      for (int r = 0; r < 4; ++r) {
        red[h][l][t * 4 + r] = acc0[t][r];
        red[h][l][16 + t * 4 + r] = acc1[t][r];
      }
  }
  __syncthreads();
  if (!jh) {
#pragma unroll
    for (int t = 0; t < 4; ++t)
#pragma unroll
      for (int r = 0; r < 4; ++r) {
        acc0[t][r] += red[h][l][t * 4 + r];
        acc1[t][r] += red[h][l][16 + t * 4 + r];
      }
#pragma unroll
    for (int r = 0; r < 4; ++r) {
      int gi0 = i0 + kg * 4 + r;
      float* op0 = out + ((size_t)b * NN + gi0) * 256 + h * 64;
      op0[0 * 16 + ln] = acc0[0][r];
      op0[1 * 16 + ln] = acc0[1][r];
      op0[2 * 16 + ln] = acc0[2][r];
      op0[3 * 16 + ln] = acc0[3][r];
      float* op1 = op0 + 16 * 256;
      op1[0 * 16 + ln] = acc1[0][r];
      op1[1 * 16 + ln] = acc1[1][r];
      op1[2 * 16 + ln] = acc1[2][r];
      op1[3 * 16 + ln] = acc1[3][r];
    }
  }
}

extern "C" void kernel_launch(void* const* d_in, const int* in_sizes, int n_in,
                              void* d_out, int out_size, void* d_ws,
                              size_t ws_size, hipStream_t stream) {
  const float* A = (const float*)d_in[0];
  const float* x = (const float*)d_in[1];
  const float* W = (const float*)d_in[2];
  const float* aw = (const float*)d_in[3];
  const float* ab = (const float*)d_in[4];
  float* out = (float*)d_out;
  char* ws = (char*)d_ws;
  _Float16* WhH = (_Float16*)ws;                        // 4 MB
  _Float16* VTt = (_Float16*)(ws + (4u << 20));         // 4 MB
  _Float16* Wtt = (_Float16*)(ws + (8u << 20));         // 64 KB
  float* si2 = (float*)(ws + (8u << 20) + (256u << 10));    // 128 KB
  float* tj2 = (float*)(ws + (8u << 20) + (384u << 10));    // 128 KB
  float* part = (float*)(ws + (8u << 20) + (512u << 10));   // 2 MB (16 splits)
  unsigned long long* Abits =
      (unsigned long long*)(ws + (10u << 20) + (512u << 10));  // 1 MB

  hipLaunchKernelGGL(k0_wt, dim3(8), dim3(256), 0, stream, W, Wtt);
  hipLaunchKernelGGL(k1_whm, dim3(512), dim3(256), 0, stream, x, Wtt, aw, ab,
                     WhH, si2, tj2);
  hipLaunchKernelGGL(kb_colsum_bits, dim3(4, 16, BB), dim3(256), 0, stream, A,
                     si2, tj2, part, Abits);
  hipLaunchKernelGGL(k3_scale_tr, dim3(512), dim3(256), 0, stream, WhH, part,
                     VTt);
  hipLaunchKernelGGL(k4_pv, dim3(256), dim3(512), 0, stream, Abits, si2, tj2,
                     VTt, out);
}

// Round 6
// 49.622 us; speedup vs baseline: 1.2548x; 1.2548x over previous
//
#include <hip/hip_runtime.h>
#include <hip/hip_bf16.h>
#include <hip/hip_fp16.h>

#define BB 8
#define NN 1024
#define FIN 128
#define FOUT 64
#define HH 4
#define EPSV 1e-7f
#define SLOPE 0.2f
#define LOG2E 1.44269504088896340736f

typedef _Float16 v8h __attribute__((ext_vector_type(8)));
typedef _Float16 v4h __attribute__((ext_vector_type(4)));
typedef float v4f __attribute__((ext_vector_type(4)));

// ---------------- K0: Wtt[ct][kgg][16][8]: (ct*16+ln, kgg*8+e) of Wt --------
__global__ __launch_bounds__(256) void k0_wt(const float* __restrict__ W,
                                             _Float16* __restrict__ Wtt) {
  for (int it = 0; it < 16; ++it) {
    int idx = blockIdx.x * 4096 + it * 256 + threadIdx.x;
    int e = idx & 7, ln = (idx >> 3) & 15, kgg = (idx >> 7) & 15,
        ct = idx >> 11;
    int c = ct * 16 + ln, k = kgg * 8 + e;
    Wtt[idx] = (_Float16)W[(size_t)(c >> 6) * 8192 + k * 64 + (c & 63)];
  }
}

// ---------------- K1: Wh = x @ W via MFMA f16 + fused s_i/s_j ---------------
__global__ __launch_bounds__(256) void k1_whm(const float* __restrict__ x,
                                              const _Float16* __restrict__ Wtt,
                                              const float* __restrict__ aw,
                                              const float* __restrict__ ab,
                                              _Float16* __restrict__ WhH,
                                              float* __restrict__ si2,
                                              float* __restrict__ tj2) {
  __shared__ _Float16 xs[16][136];
  int tid = threadIdx.x;
#pragma unroll
  for (int t2 = 0; t2 < 2; ++t2) {
    int idx = t2 * 256 + tid;
    int row = idx >> 5, c4 = (idx & 31) * 4;
    float4 v = *(const float4*)(x + ((size_t)blockIdx.x * 16 + row) * FIN + c4);
    v4h hv;
    hv[0] = (_Float16)v.x; hv[1] = (_Float16)v.y;
    hv[2] = (_Float16)v.z; hv[3] = (_Float16)v.w;
    *(v4h*)(&xs[row][c4]) = hv;
  }
  __syncthreads();
  int w = tid >> 6, l = tid & 63;
  int kg = l >> 4, ln = l & 15;
  v4f acc[4] = {{}, {}, {}, {}};
#pragma unroll
  for (int ks = 0; ks < 4; ++ks) {
    v8h af = *(const v8h*)(&xs[ln][ks * 32 + kg * 8]);
    int kgg = ks * 4 + kg;
#pragma unroll
    for (int t = 0; t < 4; ++t) {
      int ct = w * 4 + t;
      v8h bf = *(const v8h*)(Wtt + (((size_t)ct * 16 + kgg) * 16 + ln) * 8);
      acc[t] = __builtin_amdgcn_mfma_f32_16x16x32_f16(af, bf, acc[t], 0, 0, 0);
    }
  }
  float a1v[4], a2v[4];
#pragma unroll
  for (int t = 0; t < 4; ++t) {
    a1v[t] = aw[w * 128 + t * 16 + ln];
    a2v[t] = aw[w * 128 + 64 + t * 16 + ln];
  }
  float abv = ab[w];
#pragma unroll
  for (int r = 0; r < 4; ++r) {
    float v1 = acc[0][r] * a1v[0] + acc[1][r] * a1v[1] +
               acc[2][r] * a1v[2] + acc[3][r] * a1v[3];
    float v2 = acc[0][r] * a2v[0] + acc[1][r] * a2v[1] +
               acc[2][r] * a2v[2] + acc[3][r] * a2v[3];
#pragma unroll
    for (int off = 1; off < 16; off <<= 1) {
      v1 += __shfl_xor(v1, off);
      v2 += __shfl_xor(v2, off);
    }
    if (ln == 0) {
      int gr = blockIdx.x * 16 + kg * 4 + r;
      int b_ = gr >> 10, n_ = gr & 1023;
      size_t row = ((size_t)b_ * HH + w) * NN + n_;
      si2[row] = v1 * LOG2E;
      tj2[row] = (v2 + abv) * LOG2E;
    }
  }
#pragma unroll
  for (int t = 0; t < 4; ++t) {
#pragma unroll
    for (int r = 0; r < 4; ++r) {
      int gr = blockIdx.x * 16 + kg * 4 + r;
      int b_ = gr >> 10, n_ = gr & 1023;
      WhH[(((size_t)b_ * HH + w) * NN + n_) * 64 + (t * 16 + ln)] =
          (_Float16)acc[t][r];
    }
  }
}

// ------- KB: column sums of exps over i (32 splits of 32) + A bit-pack ------
// grid (4 jt, 32 is, B), block 256. Batched loads -> ballots (no per-load
// convergent stall). Lane c*8+q keeps the ballot word of row c*8+q.
__global__ __launch_bounds__(256) void kb_colsum_bits(
    const float* __restrict__ A, const float* __restrict__ si2,
    const float* __restrict__ tj2, float* __restrict__ part,
    unsigned long long* __restrict__ Abits) {
  __shared__ float sil[4][32];
  int b = blockIdx.z, is = blockIdx.y, jt = blockIdx.x;
  int tid = threadIdx.x;
  int w = tid >> 6, lane = tid & 63;
  int j = jt * 256 + tid;
  int i0 = is * 32;
  if (tid < 128) {
    int h = tid >> 5, ii = tid & 31;
    sil[h][ii] = si2[((size_t)(b * HH + h)) * NN + i0 + ii];
  }
  __syncthreads();
  float tjv[4], acc[4] = {0.f, 0.f, 0.f, 0.f};
#pragma unroll
  for (int h = 0; h < 4; ++h) tjv[h] = tj2[((size_t)(b * HH + h)) * NN + j];
  const float* Ap = A + ((size_t)b * NN + i0) * NN + j;
  unsigned long long myword = 0ull;
#pragma unroll
  for (int c = 0; c < 4; ++c) {
    float av[8];
#pragma unroll
    for (int q = 0; q < 8; ++q)
      av[q] = Ap[(size_t)(c * 8 + q) * NN];  // 8 loads in flight
#pragma unroll
    for (int q = 0; q < 8; ++q) {
      unsigned long long m = __ballot(av[q] != 0.0f);
      if (lane == c * 8 + q) myword = m;
      int ii = c * 8 + q;
#pragma unroll
      for (int h = 0; h < 4; ++h) {
        float f = sil[h][ii] + tjv[h];
        float g = fmaxf(f, SLOPE * f);
        acc[h] += av[q] * __builtin_amdgcn_exp2f(g);
      }
    }
  }
  if (lane < 32)
    Abits[((size_t)b * NN + i0 + lane) * 16 + jt * 4 + w] = myword;
#pragma unroll
  for (int h = 0; h < 4; ++h)
    part[((size_t)(is * 32) + b * HH + h) * NN + j] = acc[h];
}

// ---------------- K3: r[j]=1/(colsum+eps); VTt[bh][jb][o][jj] = (f16) r*Wh --
__global__ __launch_bounds__(256) void k3_scale_tr(
    const _Float16* __restrict__ WhH, const float* __restrict__ part,
    _Float16* __restrict__ VTt) {
  __shared__ float rbuf[64];
  __shared__ _Float16 tile[64 * 66];
  int bid = blockIdx.x;
  int b = bid & 7, rest = bid >> 3;
  int h = rest & 3, jt = rest >> 2;
  int bh = b * HH + h, j0 = jt * 64;
  int tid = threadIdx.x;
  if (tid < 64) {
    float s = 0.f;
#pragma unroll
    for (int is = 0; is < 32; ++is)
      s += part[((size_t)(is * 32) + bh) * NN + j0 + tid];
    rbuf[tid] = 1.0f / (s + EPSV);
  }
  __syncthreads();
#pragma unroll
  for (int it = 0; it < 16; ++it) {
    int lin = it * 256 + tid;
    int jj = lin >> 6, o = lin & 63;
    float v = (float)WhH[((size_t)bh * NN + j0 + jj) * 64 + o] * rbuf[jj];
    tile[o * 66 + jj] = (_Float16)v;
  }
  __syncthreads();
#pragma unroll
  for (int it = 0; it < 16; ++it) {
    int lin = it * 256 + tid;
    int o = lin >> 6, jj64 = lin & 63;
    int j = j0 + jj64;
    int jb = j >> 5, jj = j & 31;
    VTt[(((size_t)bh * 32 + jb) * 64 + o) * 32 + jj] = tile[o * 66 + jj64];
  }
}

// ---------------- K4: out[i,:] = sum_j P[i,j] * V'[j,:] via MFMA ------------
// grid 256 1D (b = bid&7 -> XCD-local VT), block 512 = 8 waves.
// wave w: head = w&3, j-half = w>>2 (512 js). 32 i-rows per block from Abits.
__global__ __launch_bounds__(512) void k4_pv(
    const unsigned long long* __restrict__ Abits,
    const float* __restrict__ si2, const float* __restrict__ tj2,
    const _Float16* __restrict__ VTt, float* __restrict__ out) {
  __shared__ unsigned long long Ab[32][17];
  __shared__ float tjl[4][1024];
  __shared__ float sil[4][32];
  __shared__ float red[4][64][33];
  int bid = blockIdx.x;
  int b = bid & 7, it = bid >> 3;
  int i0 = it * 32;
  int tid = threadIdx.x;
#pragma unroll
  for (int t2 = 0; t2 < 8; ++t2) {
    int idx = t2 * 512 + tid;
    int h = idx >> 10, j = idx & 1023;
    tjl[h][j] = tj2[((size_t)(b * HH + h)) * NN + j];
  }
  if (tid < 128) {
    int h = tid >> 5, ii = tid & 31;
    sil[h][ii] = si2[((size_t)(b * HH + h)) * NN + i0 + ii];
  }
  {
    int row = tid >> 4, word = tid & 15;
    Ab[row][word] = Abits[((size_t)b * NN + i0 + row) * 16 + word];
  }
  __syncthreads();

  int w = tid >> 6, l = tid & 63;
  int h = w & 3, jh = w >> 2;
  int kg = l >> 4, ln = l & 15;
  float si0 = sil[h][ln];
  float si1 = sil[h][16 + ln];
  int bh = b * HH + h;
  v4f acc0[4] = {{}, {}, {}, {}};
  v4f acc1[4] = {{}, {}, {}, {}};
  const _Float16* VTb = VTt + (size_t)bh * 32 * 64 * 32;
  const float* tj = tjl[h];
  int jbase = jh * 512;

#define PEXP(si, tv) \
  __builtin_amdgcn_exp2f(fmaxf((si) + (tv), SLOPE * ((si) + (tv))))

#pragma unroll 2
  for (int jq = 0; jq < 16; ++jq) {
    int j = jbase + jq * 32 + kg * 8;
    int widx = j >> 6, sh = j & 63;
    unsigned int bits0 = (unsigned int)(Ab[ln][widx] >> sh) & 0xffu;
    unsigned int bits1 = (unsigned int)(Ab[16 + ln][widx] >> sh) & 0xffu;
    float4 t0 = *(const float4*)(tj + j);
    float4 t1 = *(const float4*)(tj + j + 4);
    v8h af0, af1;
    af0[0] = (bits0 & 1u) ? (_Float16)PEXP(si0, t0.x) : (_Float16)0;
    af0[1] = (bits0 & 2u) ? (_Float16)PEXP(si0, t0.y) : (_Float16)0;
    af0[2] = (bits0 & 4u) ? (_Float16)PEXP(si0, t0.z) : (_Float16)0;
    af0[3] = (bits0 & 8u) ? (_Float16)PEXP(si0, t0.w) : (_Float16)0;
    af0[4] = (bits0 & 16u) ? (_Float16)PEXP(si0, t1.x) : (_Float16)0;
    af0[5] = (bits0 & 32u) ? (_Float16)PEXP(si0, t1.y) : (_Float16)0;
    af0[6] = (bits0 & 64u) ? (_Float16)PEXP(si0, t1.z) : (_Float16)0;
    af0[7] = (bits0 & 128u) ? (_Float16)PEXP(si0, t1.w) : (_Float16)0;
    af1[0] = (bits1 & 1u) ? (_Float16)PEXP(si1, t0.x) : (_Float16)0;
    af1[1] = (bits1 & 2u) ? (_Float16)PEXP(si1, t0.y) : (_Float16)0;
    af1[2] = (bits1 & 4u) ? (_Float16)PEXP(si1, t0.z) : (_Float16)0;
    af1[3] = (bits1 & 8u) ? (_Float16)PEXP(si1, t0.w) : (_Float16)0;
    af1[4] = (bits1 & 16u) ? (_Float16)PEXP(si1, t1.x) : (_Float16)0;
    af1[5] = (bits1 & 32u) ? (_Float16)PEXP(si1, t1.y) : (_Float16)0;
    af1[6] = (bits1 & 64u) ? (_Float16)PEXP(si1, t1.z) : (_Float16)0;
    af1[7] = (bits1 & 128u) ? (_Float16)PEXP(si1, t1.w) : (_Float16)0;
    const _Float16* vb = VTb + (size_t)(j >> 5) * 2048 + kg * 8;
    v8h b0 = *(const v8h*)(vb + (0 * 16 + ln) * 32);
    v8h b1 = *(const v8h*)(vb + (1 * 16 + ln) * 32);
    v8h b2 = *(const v8h*)(vb + (2 * 16 + ln) * 32);
    v8h b3 = *(const v8h*)(vb + (3 * 16 + ln) * 32);
    acc0[0] = __builtin_amdgcn_mfma_f32_16x16x32_f16(af0, b0, acc0[0], 0, 0, 0);
    acc1[0] = __builtin_amdgcn_mfma_f32_16x16x32_f16(af1, b0, acc1[0], 0, 0, 0);
    acc0[1] = __builtin_amdgcn_mfma_f32_16x16x32_f16(af0, b1, acc0[1], 0, 0, 0);
    acc1[1] = __builtin_amdgcn_mfma_f32_16x16x32_f16(af1, b1, acc1[1], 0, 0, 0);
    acc0[2] = __builtin_amdgcn_mfma_f32_16x16x32_f16(af0, b2, acc0[2], 0, 0, 0);
    acc1[2] = __builtin_amdgcn_mfma_f32_16x16x32_f16(af1, b2, acc1[2], 0, 0, 0);
    acc0[3] = __builtin_amdgcn_mfma_f32_16x16x32_f16(af0, b3, acc0[3], 0, 0, 0);
    acc1[3] = __builtin_amdgcn_mfma_f32_16x16x32_f16(af1, b3, acc1[3], 0, 0, 0);
  }
#undef PEXP

  if (jh) {
#pragma unroll
    for (int t = 0; t < 4; ++t)
#pragma unroll
      for (int r = 0; r < 4; ++r) {
        red[h][l][t * 4 + r] = acc0[t][r];
        red[h][l][16 + t * 4 + r] = acc1[t][r];
      }
  }
  __syncthreads();
  if (!jh) {
#pragma unroll
    for (int t = 0; t < 4; ++t)
#pragma unroll
      for (int r = 0; r < 4; ++r) {
        acc0[t][r] += red[h][l][t * 4 + r];
        acc1[t][r] += red[h][l][16 + t * 4 + r];
      }
#pragma unroll
    for (int r = 0; r < 4; ++r) {
      int gi0 = i0 + kg * 4 + r;
      float* op0 = out + ((size_t)b * NN + gi0) * 256 + h * 64;
      op0[0 * 16 + ln] = acc0[0][r];
      op0[1 * 16 + ln] = acc0[1][r];
      op0[2 * 16 + ln] = acc0[2][r];
      op0[3 * 16 + ln] = acc0[3][r];
      float* op1 = op0 + 16 * 256;
      op1[0 * 16 + ln] = acc1[0][r];
      op1[1 * 16 + ln] = acc1[1][r];
      op1[2 * 16 + ln] = acc1[2][r];
      op1[3 * 16 + ln] = acc1[3][r];
    }
  }
}

extern "C" void kernel_launch(void* const* d_in, const int* in_sizes, int n_in,
                              void* d_out, int out_size, void* d_ws,
                              size_t ws_size, hipStream_t stream) {
  const float* A = (const float*)d_in[0];
  const float* x = (const float*)d_in[1];
  const float* W = (const float*)d_in[2];
  const float* aw = (const float*)d_in[3];
  const float* ab = (const float*)d_in[4];
  float* out = (float*)d_out;
  char* ws = (char*)d_ws;
  _Float16* WhH = (_Float16*)ws;                        // 4 MB
  _Float16* VTt = (_Float16*)(ws + (4u << 20));         // 4 MB
  _Float16* Wtt = (_Float16*)(ws + (8u << 20));         // 64 KB
  float* si2 = (float*)(ws + (8u << 20) + (256u << 10));    // 128 KB
  float* tj2 = (float*)(ws + (8u << 20) + (384u << 10));    // 128 KB
  float* part = (float*)(ws + (8u << 20) + (512u << 10));   // 4 MB (32 splits)
  unsigned long long* Abits =
      (unsigned long long*)(ws + (12u << 20) + (512u << 10));  // 1 MB

  hipLaunchKernelGGL(k0_wt, dim3(8), dim3(256), 0, stream, W, Wtt);
  hipLaunchKernelGGL(k1_whm, dim3(512), dim3(256), 0, stream, x, Wtt, aw, ab,
                     WhH, si2, tj2);
  hipLaunchKernelGGL(kb_colsum_bits, dim3(4, 32, BB), dim3(256), 0, stream, A,
                     si2, tj2, part, Abits);
  hipLaunchKernelGGL(k3_scale_tr, dim3(512), dim3(256), 0, stream, WhH, part,
                     VTt);
  hipLaunchKernelGGL(k4_pv, dim3(256), dim3(512), 0, stream, Abits, si2, tj2,
                     VTt, out);
}

// Round 8
// 48.600 us; speedup vs baseline: 1.2812x; 1.0210x over previous
//
#include <hip/hip_runtime.h>
#include <hip/hip_bf16.h>
#include <hip/hip_fp16.h>

#define BB 8
#define NN 1024
#define FIN 128
#define FOUT 64
#define HH 4
#define EPSV 1e-7f
#define SLOPE 0.2f
#define LOG2E 1.44269504088896340736f

typedef _Float16 v8h __attribute__((ext_vector_type(8)));
typedef _Float16 v4h __attribute__((ext_vector_type(4)));
typedef __fp16 v2hf __attribute__((ext_vector_type(2)));
typedef float v4f __attribute__((ext_vector_type(4)));

// ---------------- K0: Wtt[ct][kgg][16][8]: (ct*16+ln, kgg*8+e) of Wt --------
__global__ __launch_bounds__(256) void k0_wt(const float* __restrict__ W,
                                             _Float16* __restrict__ Wtt) {
  for (int it = 0; it < 16; ++it) {
    int idx = blockIdx.x * 4096 + it * 256 + threadIdx.x;
    int e = idx & 7, ln = (idx >> 3) & 15, kgg = (idx >> 7) & 15,
        ct = idx >> 11;
    int c = ct * 16 + ln, k = kgg * 8 + e;
    Wtt[idx] = (_Float16)W[(size_t)(c >> 6) * 8192 + k * 64 + (c & 63)];
  }
}

// ---------------- K1: Wh = x @ W via MFMA f16 + fused s_i/s_j ---------------
__global__ __launch_bounds__(256) void k1_whm(const float* __restrict__ x,
                                              const _Float16* __restrict__ Wtt,
                                              const float* __restrict__ aw,
                                              const float* __restrict__ ab,
                                              _Float16* __restrict__ WhH,
                                              float* __restrict__ si2,
                                              float* __restrict__ tj2) {
  __shared__ _Float16 xs[16][136];
  int tid = threadIdx.x;
#pragma unroll
  for (int t2 = 0; t2 < 2; ++t2) {
    int idx = t2 * 256 + tid;
    int row = idx >> 5, c4 = (idx & 31) * 4;
    float4 v = *(const float4*)(x + ((size_t)blockIdx.x * 16 + row) * FIN + c4);
    v4h hv;
    hv[0] = (_Float16)v.x; hv[1] = (_Float16)v.y;
    hv[2] = (_Float16)v.z; hv[3] = (_Float16)v.w;
    *(v4h*)(&xs[row][c4]) = hv;
  }
  __syncthreads();
  int w = tid >> 6, l = tid & 63;
  int kg = l >> 4, ln = l & 15;
  v4f acc[4] = {{}, {}, {}, {}};
#pragma unroll
  for (int ks = 0; ks < 4; ++ks) {
    v8h af = *(const v8h*)(&xs[ln][ks * 32 + kg * 8]);
    int kgg = ks * 4 + kg;
#pragma unroll
    for (int t = 0; t < 4; ++t) {
      int ct = w * 4 + t;
      v8h bf = *(const v8h*)(Wtt + (((size_t)ct * 16 + kgg) * 16 + ln) * 8);
      acc[t] = __builtin_amdgcn_mfma_f32_16x16x32_f16(af, bf, acc[t], 0, 0, 0);
    }
  }
  float a1v[4], a2v[4];
#pragma unroll
  for (int t = 0; t < 4; ++t) {
    a1v[t] = aw[w * 128 + t * 16 + ln];
    a2v[t] = aw[w * 128 + 64 + t * 16 + ln];
  }
  float abv = ab[w];
#pragma unroll
  for (int r = 0; r < 4; ++r) {
    float v1 = acc[0][r] * a1v[0] + acc[1][r] * a1v[1] +
               acc[2][r] * a1v[2] + acc[3][r] * a1v[3];
    float v2 = acc[0][r] * a2v[0] + acc[1][r] * a2v[1] +
               acc[2][r] * a2v[2] + acc[3][r] * a2v[3];
#pragma unroll
    for (int off = 1; off < 16; off <<= 1) {
      v1 += __shfl_xor(v1, off);
      v2 += __shfl_xor(v2, off);
    }
    if (ln == 0) {
      int gr = blockIdx.x * 16 + kg * 4 + r;
      int b_ = gr >> 10, n_ = gr & 1023;
      size_t row = ((size_t)b_ * HH + w) * NN + n_;
      si2[row] = v1 * LOG2E;
      tj2[row] = (v2 + abv) * LOG2E;
    }
  }
#pragma unroll
  for (int t = 0; t < 4; ++t) {
#pragma unroll
    for (int r = 0; r < 4; ++r) {
      int gr = blockIdx.x * 16 + kg * 4 + r;
      int b_ = gr >> 10, n_ = gr & 1023;
      WhH[(((size_t)b_ * HH + w) * NN + n_) * 64 + (t * 16 + ln)] =
          (_Float16)acc[t][r];
    }
  }
}

// ------- KB: column sums of exps over i (32 splits of 32) + A bit-pack ------
__global__ __launch_bounds__(256) void kb_colsum_bits(
    const float* __restrict__ A, const float* __restrict__ si2,
    const float* __restrict__ tj2, float* __restrict__ part,
    unsigned long long* __restrict__ Abits) {
  __shared__ float sil[4][32];
  int b = blockIdx.z, is = blockIdx.y, jt = blockIdx.x;
  int tid = threadIdx.x;
  int w = tid >> 6, lane = tid & 63;
  int j = jt * 256 + tid;
  int i0 = is * 32;
  if (tid < 128) {
    int h = tid >> 5, ii = tid & 31;
    sil[h][ii] = si2[((size_t)(b * HH + h)) * NN + i0 + ii];
  }
  __syncthreads();
  float tjv[4], acc[4] = {0.f, 0.f, 0.f, 0.f};
#pragma unroll
  for (int h = 0; h < 4; ++h) tjv[h] = tj2[((size_t)(b * HH + h)) * NN + j];
  const float* Ap = A + ((size_t)b * NN + i0) * NN + j;
  unsigned long long myword = 0ull;
#pragma unroll
  for (int c = 0; c < 4; ++c) {
    float av[8];
#pragma unroll
    for (int q = 0; q < 8; ++q)
      av[q] = Ap[(size_t)(c * 8 + q) * NN];
#pragma unroll
    for (int q = 0; q < 8; ++q) {
      unsigned long long m = __ballot(av[q] != 0.0f);
      if (lane == c * 8 + q) myword = m;
      int ii = c * 8 + q;
#pragma unroll
      for (int h = 0; h < 4; ++h) {
        float f = sil[h][ii] + tjv[h];
        float g = fmaxf(f, SLOPE * f);
        acc[h] += av[q] * __builtin_amdgcn_exp2f(g);
      }
    }
  }
  if (lane < 32)
    Abits[((size_t)b * NN + i0 + lane) * 16 + jt * 4 + w] = myword;
#pragma unroll
  for (int h = 0; h < 4; ++h)
    part[((size_t)(is * 32) + b * HH + h) * NN + j] = acc[h];
}

// ---------------- K3: r[j]=1/(colsum+eps); VTt[bh][jb][o][jj] = (f16) r*Wh --
__global__ __launch_bounds__(256) void k3_scale_tr(
    const _Float16* __restrict__ WhH, const float* __restrict__ part,
    _Float16* __restrict__ VTt) {
  __shared__ float rbuf[64];
  __shared__ _Float16 tile[64 * 66];
  int bid = blockIdx.x;
  int b = bid & 7, rest = bid >> 3;
  int h = rest & 3, jt = rest >> 2;
  int bh = b * HH + h, j0 = jt * 64;
  int tid = threadIdx.x;
  if (tid < 64) {
    float s = 0.f;
#pragma unroll
    for (int is = 0; is < 32; ++is)
      s += part[((size_t)(is * 32) + bh) * NN + j0 + tid];
    rbuf[tid] = 1.0f / (s + EPSV);
  }
  __syncthreads();
#pragma unroll
  for (int it = 0; it < 16; ++it) {
    int lin = it * 256 + tid;
    int jj = lin >> 6, o = lin & 63;
    float v = (float)WhH[((size_t)bh * NN + j0 + jj) * 64 + o] * rbuf[jj];
    tile[o * 66 + jj] = (_Float16)v;
  }
  __syncthreads();
#pragma unroll
  for (int it = 0; it < 16; ++it) {
    int lin = it * 256 + tid;
    int o = lin >> 6, jj64 = lin & 63;
    int j = j0 + jj64;
    int jb = j >> 5, jj = j & 31;
    VTt[(((size_t)bh * 32 + jb) * 64 + o) * 32 + jj] = tile[o * 66 + jj64];
  }
}

// ---------------- K4: out[i,:] = sum_j P[i,j] * V'[j,:] via MFMA ------------
// grid 512 1D: b = bid&7 (XCD-local VT), hp = (bid>>3)&1 (head pair),
// it = bid>>4 (32-row i-tile). block 512 = 8 waves = (2 heads x 4 j-quarters)
// -> 2 blocks/CU, 4 waves/SIMD. 4-way j-quarter reduce via 2 pairwise stages.
__global__ __launch_bounds__(512, 4) void k4_pv(
    const unsigned long long* __restrict__ Abits,
    const float* __restrict__ si2, const float* __restrict__ tj2,
    const _Float16* __restrict__ VTt, float* __restrict__ out) {
  __shared__ unsigned long long Ab[32][17];
  __shared__ float tjl[2][1024];
  __shared__ float sil[2][32];
  __shared__ float red[2][2][64][32];
  int bid = blockIdx.x;
  int b = bid & 7, hp = (bid >> 3) & 1, it = bid >> 4;
  int i0 = it * 32;
  int tid = threadIdx.x;
#pragma unroll
  for (int t2 = 0; t2 < 4; ++t2) {
    int idx = t2 * 512 + tid;
    int hh = idx >> 10, j = idx & 1023;
    tjl[hh][j] = tj2[((size_t)(b * HH + hp * 2 + hh)) * NN + j];
  }
  if (tid < 64) {
    int hh = tid >> 5, ii = tid & 31;
    sil[hh][ii] = si2[((size_t)(b * HH + hp * 2 + hh)) * NN + i0 + ii];
  }
  {
    int row = tid >> 4, word = tid & 15;
    if (word < 16) Ab[row][word] = Abits[((size_t)b * NN + i0 + row) * 16 + word];
  }
  __syncthreads();

  int w = tid >> 6, l = tid & 63;
  int hh = w & 1, jq4 = w >> 1;  // head-in-pair, j-quarter
  int kg = l >> 4, ln = l & 15;
  float si0 = sil[hh][ln];
  float si1 = sil[hh][16 + ln];
  int bh = b * HH + hp * 2 + hh;
  v4f acc0[4] = {{}, {}, {}, {}};
  v4f acc1[4] = {{}, {}, {}, {}};
  const _Float16* VTb = VTt + (size_t)bh * 32 * 64 * 32;
  const float* tj = tjl[hh];
  int jbase = jq4 * 256;

#define PEXP(si, tv) \
  __builtin_amdgcn_exp2f(fmaxf((si) + (tv), SLOPE * ((si) + (tv))))

#pragma unroll 2
  for (int jq = 0; jq < 8; ++jq) {
    int j = jbase + jq * 32 + kg * 8;
    int widx = j >> 6, sh = j & 63;
    unsigned int bits0 = (unsigned int)(Ab[ln][widx] >> sh) & 0xffu;
    unsigned int bits1 = (unsigned int)(Ab[16 + ln][widx] >> sh) & 0xffu;
    float4 t0 = *(const float4*)(tj + j);
    float4 t1 = *(const float4*)(tj + j + 4);
    float p0[8], p1[8];
    p0[0] = (bits0 & 1u) ? PEXP(si0, t0.x) : 0.f;
    p0[1] = (bits0 & 2u) ? PEXP(si0, t0.y) : 0.f;
    p0[2] = (bits0 & 4u) ? PEXP(si0, t0.z) : 0.f;
    p0[3] = (bits0 & 8u) ? PEXP(si0, t0.w) : 0.f;
    p0[4] = (bits0 & 16u) ? PEXP(si0, t1.x) : 0.f;
    p0[5] = (bits0 & 32u) ? PEXP(si0, t1.y) : 0.f;
    p0[6] = (bits0 & 64u) ? PEXP(si0, t1.z) : 0.f;
    p0[7] = (bits0 & 128u) ? PEXP(si0, t1.w) : 0.f;
    p1[0] = (bits1 & 1u) ? PEXP(si1, t0.x) : 0.f;
    p1[1] = (bits1 & 2u) ? PEXP(si1, t0.y) : 0.f;
    p1[2] = (bits1 & 4u) ? PEXP(si1, t0.z) : 0.f;
    p1[3] = (bits1 & 8u) ? PEXP(si1, t0.w) : 0.f;
    p1[4] = (bits1 & 16u) ? PEXP(si1, t1.x) : 0.f;
    p1[5] = (bits1 & 32u) ? PEXP(si1, t1.y) : 0.f;
    p1[6] = (bits1 & 64u) ? PEXP(si1, t1.z) : 0.f;
    p1[7] = (bits1 & 128u) ? PEXP(si1, t1.w) : 0.f;
    union { v2hf h2[4]; v8h h8; } u0, u1;
#pragma unroll
    for (int q = 0; q < 4; ++q) {
      u0.h2[q] = __builtin_amdgcn_cvt_pkrtz(p0[2 * q], p0[2 * q + 1]);
      u1.h2[q] = __builtin_amdgcn_cvt_pkrtz(p1[2 * q], p1[2 * q + 1]);
    }
    v8h af0 = u0.h8, af1 = u1.h8;
    const _Float16* vb = VTb + (size_t)(j >> 5) * 2048 + kg * 8;
    v8h b0 = *(const v8h*)(vb + (0 * 16 + ln) * 32);
    v8h b1 = *(const v8h*)(vb + (1 * 16 + ln) * 32);
    v8h b2 = *(const v8h*)(vb + (2 * 16 + ln) * 32);
    v8h b3 = *(const v8h*)(vb + (3 * 16 + ln) * 32);
    acc0[0] = __builtin_amdgcn_mfma_f32_16x16x32_f16(af0, b0, acc0[0], 0, 0, 0);
    acc1[0] = __builtin_amdgcn_mfma_f32_16x16x32_f16(af1, b0, acc1[0], 0, 0, 0);
    acc0[1] = __builtin_amdgcn_mfma_f32_16x16x32_f16(af0, b1, acc0[1], 0, 0, 0);
    acc1[1] = __builtin_amdgcn_mfma_f32_16x16x32_f16(af1, b1, acc1[1], 0, 0, 0);
    acc0[2] = __builtin_amdgcn_mfma_f32_16x16x32_f16(af0, b2, acc0[2], 0, 0, 0);
    acc1[2] = __builtin_amdgcn_mfma_f32_16x16x32_f16(af1, b2, acc1[2], 0, 0, 0);
    acc0[3] = __builtin_amdgcn_mfma_f32_16x16x32_f16(af0, b3, acc0[3], 0, 0, 0);
    acc1[3] = __builtin_amdgcn_mfma_f32_16x16x32_f16(af1, b3, acc1[3], 0, 0, 0);
  }
#undef PEXP

  // 4-way j-quarter reduce, two pairwise stages. slots: [hh][0|1]
  if (jq4 == 1 || jq4 == 3) {
    int slot = jq4 >> 1;  // q1->0, q3->1
#pragma unroll
    for (int t = 0; t < 4; ++t)
#pragma unroll
      for (int r = 0; r < 4; ++r) {
        red[hh][slot][l][t * 4 + r] = acc0[t][r];
        red[hh][slot][l][16 + t * 4 + r] = acc1[t][r];
      }
  }
  __syncthreads();
  if (jq4 == 0 || jq4 == 2) {
    int slot = jq4 >> 1;
#pragma unroll
    for (int t = 0; t < 4; ++t)
#pragma unroll
      for (int r = 0; r < 4; ++r) {
        acc0[t][r] += red[hh][slot][l][t * 4 + r];
        acc1[t][r] += red[hh][slot][l][16 + t * 4 + r];
      }
  }
  __syncthreads();
  if (jq4 == 2) {
#pragma unroll
    for (int t = 0; t < 4; ++t)
#pragma unroll
      for (int r = 0; r < 4; ++r) {
        red[hh][0][l][t * 4 + r] = acc0[t][r];
        red[hh][0][l][16 + t * 4 + r] = acc1[t][r];
      }
  }
  __syncthreads();
  if (jq4 == 0) {
#pragma unroll
    for (int t = 0; t < 4; ++t)
#pragma unroll
      for (int r = 0; r < 4; ++r) {
        acc0[t][r] += red[hh][0][l][t * 4 + r];
        acc1[t][r] += red[hh][0][l][16 + t * 4 + r];
      }
#pragma unroll
    for (int r = 0; r < 4; ++r) {
      int gi0 = i0 + kg * 4 + r;
      float* op0 = out + ((size_t)b * NN + gi0) * 256 + (hp * 2 + hh) * 64;
      op0[0 * 16 + ln] = acc0[0][r];
      op0[1 * 16 + ln] = acc0[1][r];
      op0[2 * 16 + ln] = acc0[2][r];
      op0[3 * 16 + ln] = acc0[3][r];
      float* op1 = op0 + 16 * 256;
      op1[0 * 16 + ln] = acc1[0][r];
      op1[1 * 16 + ln] = acc1[1][r];
      op1[2 * 16 + ln] = acc1[2][r];
      op1[3 * 16 + ln] = acc1[3][r];
    }
  }
}

extern "C" void kernel_launch(void* const* d_in, const int* in_sizes, int n_in,
                              void* d_out, int out_size, void* d_ws,
                              size_t ws_size, hipStream_t stream) {
  const float* A = (const float*)d_in[0];
  const float* x = (const float*)d_in[1];
  const float* W = (const float*)d_in[2];
  const float* aw = (const float*)d_in[3];
  const float* ab = (const float*)d_in[4];
  float* out = (float*)d_out;
  char* ws = (char*)d_ws;
  _Float16* WhH = (_Float16*)ws;                        // 4 MB
  _Float16* VTt = (_Float16*)(ws + (4u << 20));         // 4 MB
  _Float16* Wtt = (_Float16*)(ws + (8u << 20));         // 64 KB
  float* si2 = (float*)(ws + (8u << 20) + (256u << 10));    // 128 KB
  float* tj2 = (float*)(ws + (8u << 20) + (384u << 10));    // 128 KB
  float* part = (float*)(ws + (8u << 20) + (512u << 10));   // 4 MB (32 splits)
  unsigned long long* Abits =
      (unsigned long long*)(ws + (12u << 20) + (512u << 10));  // 1 MB

  hipLaunchKernelGGL(k0_wt, dim3(8), dim3(256), 0, stream, W, Wtt);
  hipLaunchKernelGGL(k1_whm, dim3(512), dim3(256), 0, stream, x, Wtt, aw, ab,
                     WhH, si2, tj2);
  hipLaunchKernelGGL(kb_colsum_bits, dim3(4, 32, BB), dim3(256), 0, stream, A,
                     si2, tj2, part, Abits);
  hipLaunchKernelGGL(k3_scale_tr, dim3(512), dim3(256), 0, stream, WhH, part,
                     VTt);
  hipLaunchKernelGGL(k4_pv, dim3(512), dim3(512), 0, stream, Abits, si2, tj2,
                     VTt, out);
}